// Round 2
// baseline (333.885 us; speedup 1.0000x reference)
//
#include <hip/hip_runtime.h>

// EncoderBlock: pre-LN MHSA + pre-LN GELU FFN.  S=2048 D=1024 H=16 DK=64 MLP=4096.
// All GEMMs: bf16 MFMA 16x16x32, m97-style bt-GEMM (A[M,K] x Bt[N,K]), 128x128 tile,
// XOR-swizzled LDS.  N=1024 GEMMs (O-proj, FFN2) use split-K + fused reduce.
// Attention: flash, 16x16x32 MFMA (all fragment maps verified), SWAPPED QK^T
// (mfma(K,Q)) -> lane-local softmax (q = lane&15), uint2-packed P writes,
// T14 async-stage split (issue next tile's global loads under compute).

constexpr int kS = 2048, kD = 1024, kH = 16, kDK = 64, kMLP = 4096;
constexpr float kEps = 1e-5f;

using u16 = unsigned short;
using u32 = unsigned int;
typedef float f32x4 __attribute__((ext_vector_type(4)));
typedef short bf16x8 __attribute__((ext_vector_type(8)));   // 8 bf16 = 4 VGPRs

__device__ __forceinline__ u16 f2b(float f) {               // fp32 -> bf16 (RNE)
  u32 u = __builtin_bit_cast(u32, f);
  return (u16)((u + 0x7fffu + ((u >> 16) & 1u)) >> 16);
}

typedef const __attribute__((address_space(1))) u32* gas1;
typedef __attribute__((address_space(3))) u32* las3;
__device__ __forceinline__ void async16(const void* g, void* l) {
  // global -> LDS DMA, 16B/lane; LDS dest = wave-uniform base + lane*16
  __builtin_amdgcn_global_load_lds((gas1)g, (las3)l, 16, 0, 0);
}

// ---------------- LayerNorm: fp32 [row][1024] -> bf16 ----------------
__global__ __launch_bounds__(256)
void ln_kernel(const float* __restrict__ x, const float* __restrict__ g,
               const float* __restrict__ b, u16* __restrict__ out) {
  __shared__ float red[8];
  const int row = blockIdx.x, tid = threadIdx.x;
  const float4 v = *(const float4*)(x + (size_t)row * kD + tid * 4);
  float s = v.x + v.y + v.z + v.w;
  float ss = v.x * v.x + v.y * v.y + v.z * v.z + v.w * v.w;
#pragma unroll
  for (int d = 1; d < 64; d <<= 1) { s += __shfl_xor(s, d); ss += __shfl_xor(ss, d); }
  if ((tid & 63) == 0) { red[tid >> 6] = s; red[4 + (tid >> 6)] = ss; }
  __syncthreads();
  const float m = (red[0] + red[1] + red[2] + red[3]) * (1.f / kD);
  const float var = (red[4] + red[5] + red[6] + red[7]) * (1.f / kD) - m * m;
  const float r = rsqrtf(var + kEps);
  const float4 gv = *(const float4*)(g + tid * 4);
  const float4 bv = *(const float4*)(b + tid * 4);
  ushort4 o;
  o.x = f2b((v.x - m) * r * gv.x + bv.x);
  o.y = f2b((v.y - m) * r * gv.y + bv.y);
  o.z = f2b((v.z - m) * r * gv.z + bv.z);
  o.w = f2b((v.w - m) * r * gv.w + bv.w);
  *(ushort4*)(out + (size_t)row * kD + tid * 4) = o;
}

// ------------- transpose + fp32->bf16:  out[c][r] = in[r][c] -------------
__global__ __launch_bounds__(256)
void transpose_cvt(const float* __restrict__ in, u16* __restrict__ out, int R, int C) {
  __shared__ float tile[32][33];
  const int c0 = blockIdx.x * 32, r0 = blockIdx.y * 32;
  const int x = threadIdx.x, y = threadIdx.y;
#pragma unroll
  for (int i = 0; i < 4; ++i)
    tile[y + i * 8][x] = in[(size_t)(r0 + y + i * 8) * C + c0 + x];
  __syncthreads();
#pragma unroll
  for (int i = 0; i < 4; ++i)
    out[(size_t)(c0 + y + i * 8) * R + r0 + x] = f2b(tile[x][y + i * 8]);
}

__global__ void concat_bias(const float* __restrict__ bq, const float* __restrict__ bk,
                            const float* __restrict__ bv, float* __restrict__ out) {
  int i = blockIdx.x * 256 + threadIdx.x;  // 3072
  out[i] = i < kD ? bq[i] : (i < 2 * kD ? bk[i - kD] : bv[i - 2 * kD]);
}

// --- per-head V transpose: qkv[s][2048+h*64+d] (bf16) -> vt[h][d][s] (bf16) ---
__global__ __launch_bounds__(256)
void vtrans(const u16* __restrict__ qkv, u16* __restrict__ vt) {
  __shared__ u16 t[64][72];
  const int s0 = blockIdx.x * 64, h = blockIdx.y, tid = threadIdx.x;
#pragma unroll
  for (int r = 0; r < 2; ++r) {
    int chunk = r * 256 + tid, row = chunk >> 3, col = (chunk & 7) * 8;
    uint4 v = *(const uint4*)(qkv + (size_t)(s0 + row) * 3072 + 2 * kD + h * 64 + col);
    *(uint4*)(&t[row][col]) = v;
  }
  __syncthreads();
#pragma unroll
  for (int r = 0; r < 2; ++r) {
    int chunk = r * 256 + tid, drow = chunk >> 3, scol = (chunk & 7) * 8;
    u16 tmp[8];
#pragma unroll
    for (int j = 0; j < 8; ++j) tmp[j] = t[scol + j][drow];
    *(uint4*)(vt + (size_t)h * 64 * kS + (size_t)drow * kS + s0 + scol) = *(uint4*)tmp;
  }
}

// ---------------- bt-GEMM: C[M,N] = A[M,K](bf16) x Bt[N,K](bf16) ----------------
// 128x128 tile, BK=32, 4 waves, 16 MFMA/K-iter, XOR-swizzled LDS (2-way banks = free).
// EPI 0: bf16 out (+bias)   EPI 1: bf16 gelu_erf out (+bias)
// EPI 3: fp32 partial store (split-K via blockIdx.z; no bias)
template <int EPI>
__global__ __launch_bounds__(256, 2)
void gemm_bt(const u16* __restrict__ A, const u16* __restrict__ Bt,
             const float* __restrict__ bias, void* __restrict__ Cout,
             int N, int K, int Ksub) {
  constexpr int BM = 128, BN = 128, BK = 32;
  constexpr int MT = 4, NT = 4;              // 16x16 tiles per wave
  __shared__ u16 As[BM * BK];
  __shared__ u16 Bs[BN * BK];
  const int tid = threadIdx.x;
  const int w = tid >> 6, l = tid & 63;
  const int wm = w >> 1, wn = w & 1;
  const int row0 = blockIdx.y * BM, col0 = blockIdx.x * BN;
  const int koff = blockIdx.z * Ksub;

  const int sc = ((l & 3) ^ ((l >> 3) & 3)) * 8;
  const u16* Ag = A + (size_t)(row0 + w * 16 + (l >> 2)) * K + koff + sc;
  const u16* Bg = Bt + (size_t)(col0 + w * 16 + (l >> 2)) * K + koff + sc;
  u16* AsW = As + w * 512;
  u16* BsW = Bs + w * 512;

  f32x4 acc[MT][NT] = {};
  const int q = l >> 4;                      // k-chunk this lane reads for MFMA

  for (int kt = 0; kt < Ksub; kt += BK) {
#pragma unroll
    for (int r = 0; r < 2; ++r) async16(Ag + (size_t)r * 64 * K + kt, AsW + r * 2048);
#pragma unroll
    for (int r = 0; r < 2; ++r) async16(Bg + (size_t)r * 64 * K + kt, BsW + r * 2048);
    __syncthreads();  // compiler drains vmcnt before s_barrier -> LDS valid
    bf16x8 af[MT], bfr[NT];
#pragma unroll
    for (int i = 0; i < MT; ++i) {
      const int ra = wm * 64 + i * 16 + (l & 15);
      af[i] = *(const bf16x8*)(As + ra * 32 + (q ^ ((ra >> 1) & 3)) * 8);
    }
#pragma unroll
    for (int j = 0; j < NT; ++j) {
      const int rb = wn * 64 + j * 16 + (l & 15);
      bfr[j] = *(const bf16x8*)(Bs + rb * 32 + (q ^ ((rb >> 1) & 3)) * 8);
    }
#pragma unroll
    for (int i = 0; i < MT; ++i)
#pragma unroll
      for (int j = 0; j < NT; ++j)
        acc[i][j] = __builtin_amdgcn_mfma_f32_16x16x32_bf16(af[i], bfr[j], acc[i][j], 0, 0, 0);
    __syncthreads();
  }

  float* Pf = nullptr;
  if constexpr (EPI == 3)
    Pf = (float*)Cout + (size_t)blockIdx.z * gridDim.y * BM * N;
#pragma unroll
  for (int i = 0; i < MT; ++i) {
    const int row = row0 + wm * 64 + i * 16 + ((l >> 4) << 2);
#pragma unroll
    for (int j = 0; j < NT; ++j) {
      const int col = col0 + wn * 64 + j * 16 + (l & 15);
      float bb = 0.f;
      if constexpr (EPI != 3) bb = bias[col];
#pragma unroll
      for (int r = 0; r < 4; ++r) {
        const size_t idx = (size_t)(row + r) * N + col;
        float v = acc[i][j][r] + bb;
        if constexpr (EPI == 0) {
          ((u16*)Cout)[idx] = f2b(v);
        } else if constexpr (EPI == 1) {
          ((u16*)Cout)[idx] = f2b(0.5f * v * (1.f + erff(v * 0.7071067811865475f)));
        } else {
          Pf[idx] = v;
        }
      }
    }
  }
}

// ---- split-K reduce: out = sum_s parts[s] + bias + res  (fp32, float4) ----
template <int KS>
__global__ __launch_bounds__(256)
void reduce_add(const float* __restrict__ parts, const float* __restrict__ bias,
                const float* __restrict__ res, float* __restrict__ out,
                int N, size_t strideMN) {
  const size_t b = ((size_t)blockIdx.x * 256 + threadIdx.x) * 4;
  float4 a = *(const float4*)(res + b);
  const float4 bv = *(const float4*)(bias + (b & (size_t)(N - 1)));
  a.x += bv.x; a.y += bv.y; a.z += bv.z; a.w += bv.w;
#pragma unroll
  for (int s = 0; s < KS; ++s) {
    const float4 p = *(const float4*)(parts + s * strideMN + b);
    a.x += p.x; a.y += p.y; a.z += p.z; a.w += p.w;
  }
  *(float4*)(out + b) = a;
}

// ---------------- flash attention (swapped QK^T, 16x16x32) ----------------
// grid (S/64, H), 256 thr (4 waves); wave w owns q-rows [q0+w*16, +16).
// S^T = mfma(K, Q): D[k_local][q], col = lane&15 = q -> softmax is LANE-LOCAL:
// in-lane max/sum over 32 values (k = 16n + 4*(l>>4) + r) + shfl_xor(16),(32).
// P packed 4-at-a-time (uint2 = ds_write_b64) into the verified Ps[q][s] layout;
// PV + epilogue identical to the proven kernel.  T14: next tile's global loads
// are issued right after the stage barrier and land under compute.
__global__ __launch_bounds__(256, 2)
void flash_attn(const u16* __restrict__ qkv, const u16* __restrict__ vt,
                u16* __restrict__ og) {
  constexpr int LQ = 72;    // 64 + 8 pad (breaks b128 bank conflicts)
  constexpr int LV = 136;   // 128 + 8 pad
  __shared__ u16 Qs[64 * LQ];
  __shared__ u16 Ks[128 * LQ];
  __shared__ u16 Vs[64 * LV];       // V^T tile: [d][s]
  __shared__ u16 Ps[4][16 * LV];    // per-wave P[q][s]
  const int tid = threadIdx.x, w = tid >> 6, l = tid & 63;
  const int t4 = l >> 4, ln = l & 15;
  const int h = blockIdx.y, q0 = blockIdx.x * 64;

  // stage Q [64][64]
#pragma unroll
  for (int r = 0; r < 2; ++r) {
    int chunk = r * 256 + tid, row = chunk >> 3, col = (chunk & 7) * 8;
    uint4 v = *(const uint4*)(qkv + (size_t)(q0 + row) * 3072 + h * 64 + col);
    *(uint4*)(&Qs[row * LQ + col]) = v;
  }
  // prologue: issue tile-0 K/V loads into registers
  uint4 kreg[4], vreg[4];
#pragma unroll
  for (int r = 0; r < 4; ++r) {
    int chunk = r * 256 + tid, row = chunk >> 3, col = (chunk & 7) * 8;
    kreg[r] = *(const uint4*)(qkv + (size_t)row * 3072 + kD + h * 64 + col);
  }
#pragma unroll
  for (int r = 0; r < 4; ++r) {
    int chunk = r * 256 + tid, row = chunk >> 4, col = (chunk & 15) * 8;
    vreg[r] = *(const uint4*)(vt + (size_t)h * 64 * kS + (size_t)row * kS + col);
  }
  __syncthreads();   // Qs visible
  bf16x8 qa[2];
#pragma unroll
  for (int kq = 0; kq < 2; ++kq)
    qa[kq] = *(const bf16x8*)(&Qs[(w * 16 + ln) * LQ + kq * 32 + t4 * 8]);

  f32x4 oacc[4] = {};
  float mi = -1e30f, li = 0.f;

  for (int kt = 0; kt < kS; kt += 128) {
    // ---- store staged registers -> LDS (K-tile [128][64], V^T tile [64][128]) ----
#pragma unroll
    for (int r = 0; r < 4; ++r) {
      int chunk = r * 256 + tid, row = chunk >> 3, col = (chunk & 7) * 8;
      *(uint4*)(&Ks[row * LQ + col]) = kreg[r];
    }
#pragma unroll
    for (int r = 0; r < 4; ++r) {
      int chunk = r * 256 + tid, row = chunk >> 4, col = (chunk & 15) * 8;
      *(uint4*)(&Vs[row * LV + col]) = vreg[r];
    }
    __syncthreads();  // tile kt visible to all waves
    // ---- T14: issue next tile's loads; they complete under compute ----
    if (kt + 128 < kS) {
#pragma unroll
      for (int r = 0; r < 4; ++r) {
        int chunk = r * 256 + tid, row = chunk >> 3, col = (chunk & 7) * 8;
        kreg[r] = *(const uint4*)(qkv + (size_t)(kt + 128 + row) * 3072 + kD + h * 64 + col);
      }
#pragma unroll
      for (int r = 0; r < 4; ++r) {
        int chunk = r * 256 + tid, row = chunk >> 4, col = (chunk & 15) * 8;
        vreg[r] = *(const uint4*)(vt + (size_t)h * 64 * kS + (size_t)row * kS + kt + 128 + col);
      }
    }

    // ---- S^T = K Q^T : st[n] = D[k_local][q], k = 16n + 4*t4 + r, q = ln ----
    f32x4 st[8];
#pragma unroll
    for (int n = 0; n < 8; ++n) {
      f32x4 z = {};
      bf16x8 kb0 = *(const bf16x8*)(&Ks[(n * 16 + ln) * LQ + t4 * 8]);
      bf16x8 kb1 = *(const bf16x8*)(&Ks[(n * 16 + ln) * LQ + 32 + t4 * 8]);
      z = __builtin_amdgcn_mfma_f32_16x16x32_bf16(kb0, qa[0], z, 0, 0, 0);
      z = __builtin_amdgcn_mfma_f32_16x16x32_bf16(kb1, qa[1], z, 0, 0, 0);
      st[n] = z;
    }
    // ---- lane-local online softmax (q = ln; quads combined via xor 16/32) ----
    float pm = -1e30f;
#pragma unroll
    for (int n = 0; n < 8; ++n) {
      float m01 = fmaxf(st[n][0], st[n][1]);
      float m23 = fmaxf(st[n][2], st[n][3]);
      pm = fmaxf(pm, fmaxf(m01, m23));
    }
    pm = fmaxf(pm, __shfl_xor(pm, 16));
    pm = fmaxf(pm, __shfl_xor(pm, 32));
    pm *= 0.125f;  // 1/sqrt(DK); positive scale commutes with max
    const float mn = fmaxf(mi, pm);
    const float al = __expf(mi - mn);
    mi = mn;
    li *= al;
    float ar[4];
#pragma unroll
    for (int r = 0; r < 4; ++r) ar[r] = __shfl(al, t4 * 4 + r);  // alpha by q-row
#pragma unroll
    for (int n = 0; n < 4; ++n)
#pragma unroll
      for (int r = 0; r < 4; ++r) oacc[n][r] *= ar[r];
    // ---- P = exp(s*0.125 - mi); pack r-quad -> uint2 (k co-increments with r) ----
    float ls = 0.f;
#pragma unroll
    for (int n = 0; n < 8; ++n) {
      float p0 = __expf(st[n][0] * 0.125f - mi);
      float p1 = __expf(st[n][1] * 0.125f - mi);
      float p2 = __expf(st[n][2] * 0.125f - mi);
      float p3 = __expf(st[n][3] * 0.125f - mi);
      ls += (p0 + p1) + (p2 + p3);
      uint2 pk;
      pk.x = (u32)f2b(p0) | ((u32)f2b(p1) << 16);
      pk.y = (u32)f2b(p2) | ((u32)f2b(p3) << 16);
      *(uint2*)(&Ps[w][ln * LV + n * 16 + t4 * 4]) = pk;  // P[q=ln][k..k+3]
    }
    ls += __shfl_xor(ls, 16);
    ls += __shfl_xor(ls, 32);
    li += ls;
    // ---- O += P V   (P 16x128 from own-wave LDS region; V^T in Vs) ----
    bf16x8 pa[4];
#pragma unroll
    for (int ks = 0; ks < 4; ++ks)
      pa[ks] = *(const bf16x8*)(&Ps[w][ln * LV + ks * 32 + t4 * 8]);
#pragma unroll
    for (int n = 0; n < 4; ++n)
#pragma unroll
      for (int ks = 0; ks < 4; ++ks) {
        bf16x8 vb = *(const bf16x8*)(&Vs[(n * 16 + ln) * LV + ks * 32 + t4 * 8]);
        oacc[n] = __builtin_amdgcn_mfma_f32_16x16x32_bf16(pa[ks], vb, oacc[n], 0, 0, 0);
      }
    __syncthreads();   // all waves done reading Ks/Vs before next store
  }
  // epilogue: normalize, write og[h][s][d] (contiguous == reference reshape)
#pragma unroll
  for (int r = 0; r < 4; ++r) {
    float lr = __shfl(li, t4 * 4 + r);   // li lives on lanes ln = q (all quads equal)
    float inv = 1.f / lr;
    int srow = q0 + w * 16 + t4 * 4 + r;
#pragma unroll
    for (int n = 0; n < 4; ++n) {
      int d = n * 16 + ln;
      og[(size_t)h * kS * kDK + (size_t)srow * kDK + d] = f2b(oacc[n][r] * inv);
    }
  }
}

extern "C" void kernel_launch(void* const* d_in, const int* in_sizes, int n_in,
                              void* d_out, int out_size, void* d_ws, size_t ws_size,
                              hipStream_t stream) {
  const float* x = (const float*)d_in[0];
  const float* wq = (const float*)d_in[1];
  const float* bq = (const float*)d_in[2];
  const float* wk = (const float*)d_in[3];
  const float* bk = (const float*)d_in[4];
  const float* wv = (const float*)d_in[5];
  const float* bv = (const float*)d_in[6];
  const float* wo = (const float*)d_in[7];
  const float* bo = (const float*)d_in[8];
  const float* w1 = (const float*)d_in[9];
  const float* b1 = (const float*)d_in[10];
  const float* w2 = (const float*)d_in[11];
  const float* b2 = (const float*)d_in[12];
  const float* ln1g = (const float*)d_in[13];
  const float* ln1b = (const float*)d_in[14];
  const float* ln2g = (const float*)d_in[15];
  const float* ln2b = (const float*)d_in[16];
  float* out = (float*)d_out;

  // Workspace plan. "pool" buffers are all dead by the time the split-K
  // partials are written, so partials alias pool base.
  char* p = (char*)d_ws;
  auto alloc = [&](size_t bytes) { void* q = (void*)p; p += (bytes + 255) & ~(size_t)255; return q; };
  u16* h1 = (u16*)alloc((size_t)kS * kD * 2);
  u16* wqkvt = (u16*)alloc((size_t)3 * kD * kD * 2);
  u16* qkv = (u16*)alloc((size_t)kS * 3 * kD * 2);
  u16* vt = (u16*)alloc((size_t)kH * kDK * kS * 2);
  u16* og = (u16*)alloc((size_t)kS * kD * 2);
  u16* wot = (u16*)alloc((size_t)kD * kD * 2);
  u16* h2 = (u16*)alloc((size_t)kS * kD * 2);
  u16* w1t = (u16*)alloc((size_t)kD * kMLP * 2);
  float* bqkv = (float*)alloc((size_t)3 * kD * 4);
  float* x2 = (float*)alloc((size_t)kS * kD * 4);
  u16* fbuf = (u16*)alloc((size_t)kS * kMLP * 2);
  u16* w2t = (u16*)alloc((size_t)kMLP * kD * 2);
  float* part = (float*)d_ws;  // aliases pool (see plan above)
  const size_t strideMN = (size_t)kS * kD;

  dim3 tb(32, 8);
  transpose_cvt<<<dim3(kD / 32, kD / 32), tb, 0, stream>>>(wq, wqkvt, kD, kD);
  transpose_cvt<<<dim3(kD / 32, kD / 32), tb, 0, stream>>>(wk, wqkvt + kD * kD, kD, kD);
  transpose_cvt<<<dim3(kD / 32, kD / 32), tb, 0, stream>>>(wv, wqkvt + 2 * kD * kD, kD, kD);
  transpose_cvt<<<dim3(kD / 32, kD / 32), tb, 0, stream>>>(wo, wot, kD, kD);
  transpose_cvt<<<dim3(kMLP / 32, kD / 32), tb, 0, stream>>>(w1, w1t, kD, kMLP);
  transpose_cvt<<<dim3(kD / 32, kMLP / 32), tb, 0, stream>>>(w2, w2t, kMLP, kD);
  concat_bias<<<dim3(12), dim3(256), 0, stream>>>(bq, bk, bv, bqkv);

  ln_kernel<<<dim3(kS), dim3(256), 0, stream>>>(x, ln1g, ln1b, h1);
  // fused QKV: [2048,1024] x [3072,1024]^T -> qkv bf16 [2048,3072]
  gemm_bt<0><<<dim3(3 * kD / 128, kS / 128, 1), dim3(256), 0, stream>>>(
      h1, wqkvt, bqkv, qkv, 3 * kD, kD, kD);
  vtrans<<<dim3(kS / 64, kH), dim3(256), 0, stream>>>(qkv, vt);
  flash_attn<<<dim3(kS / 64, kH), dim3(256), 0, stream>>>(qkv, vt, og);
  // O-proj split-K=2: partials = og @ wo  (fp32)
  gemm_bt<3><<<dim3(kD / 128, kS / 128, 2), dim3(256), 0, stream>>>(
      og, wot, nullptr, part, kD, kD, kD / 2);
  // x2 = x + part0 + part1 + bo
  reduce_add<2><<<dim3(kS * kD / 4 / 256), dim3(256), 0, stream>>>(
      part, bo, x, x2, kD, strideMN);
  ln_kernel<<<dim3(kS), dim3(256), 0, stream>>>(x2, ln2g, ln2b, h2);
  // FFN1 + exact GELU -> bf16 [2048,4096]
  gemm_bt<1><<<dim3(kMLP / 128, kS / 128, 1), dim3(256), 0, stream>>>(
      h2, w1t, b1, fbuf, kMLP, kD, kD);
  // FFN2 split-K=4: partials = gelu @ w2  (fp32)
  gemm_bt<3><<<dim3(kD / 128, kS / 128, 4), dim3(256), 0, stream>>>(
      fbuf, w2t, nullptr, part, kD, kMLP, kMLP / 4);
  // out = x2 + sum(parts) + b2
  reduce_add<4><<<dim3(kS * kD / 4 / 256), dim3(256), 0, stream>>>(
      part, b2, x2, out, kD, strideMN);
}

// Round 3
// 331.409 us; speedup vs baseline: 1.0075x; 1.0075x over previous
//
#include <hip/hip_runtime.h>

// EncoderBlock: pre-LN MHSA + pre-LN GELU FFN.  S=2048 D=1024 H=16 DK=64 MLP=4096.
// All GEMMs: bf16 MFMA 16x16x32, bt-GEMM (A[M,K] x Bt[N,K]), 128x128 tile,
// XOR-swizzled LDS, DOUBLE-BUFFERED global_load_lds staging with counted
// s_waitcnt vmcnt(4) + raw s_barrier (T3/T4 minimum form -- never drain vmcnt
// to 0 in the main loop).  N=1024 GEMMs (O-proj, FFN2) use split-K + fused reduce.
// Attention: flash, 16x16x32 MFMA, swapped QK^T -> lane-local softmax,
// uint2-packed P writes, T14 async-stage split.

constexpr int kS = 2048, kD = 1024, kH = 16, kDK = 64, kMLP = 4096;
constexpr float kEps = 1e-5f;

using u16 = unsigned short;
using u32 = unsigned int;
typedef float f32x4 __attribute__((ext_vector_type(4)));
typedef short bf16x8 __attribute__((ext_vector_type(8)));   // 8 bf16 = 4 VGPRs

__device__ __forceinline__ u16 f2b(float f) {               // fp32 -> bf16 (RNE)
  u32 u = __builtin_bit_cast(u32, f);
  return (u16)((u + 0x7fffu + ((u >> 16) & 1u)) >> 16);
}

typedef const __attribute__((address_space(1))) u32* gas1;
typedef __attribute__((address_space(3))) u32* las3;
__device__ __forceinline__ void async16(const void* g, void* l) {
  // global -> LDS DMA, 16B/lane; LDS dest = wave-uniform base + lane*16
  __builtin_amdgcn_global_load_lds((gas1)g, (las3)l, 16, 0, 0);
}

// ---------------- LayerNorm: fp32 [row][1024] -> bf16 ----------------
__global__ __launch_bounds__(256)
void ln_kernel(const float* __restrict__ x, const float* __restrict__ g,
               const float* __restrict__ b, u16* __restrict__ out) {
  __shared__ float red[8];
  const int row = blockIdx.x, tid = threadIdx.x;
  const float4 v = *(const float4*)(x + (size_t)row * kD + tid * 4);
  float s = v.x + v.y + v.z + v.w;
  float ss = v.x * v.x + v.y * v.y + v.z * v.z + v.w * v.w;
#pragma unroll
  for (int d = 1; d < 64; d <<= 1) { s += __shfl_xor(s, d); ss += __shfl_xor(ss, d); }
  if ((tid & 63) == 0) { red[tid >> 6] = s; red[4 + (tid >> 6)] = ss; }
  __syncthreads();
  const float m = (red[0] + red[1] + red[2] + red[3]) * (1.f / kD);
  const float var = (red[4] + red[5] + red[6] + red[7]) * (1.f / kD) - m * m;
  const float r = rsqrtf(var + kEps);
  const float4 gv = *(const float4*)(g + tid * 4);
  const float4 bv = *(const float4*)(b + tid * 4);
  ushort4 o;
  o.x = f2b((v.x - m) * r * gv.x + bv.x);
  o.y = f2b((v.y - m) * r * gv.y + bv.y);
  o.z = f2b((v.z - m) * r * gv.z + bv.z);
  o.w = f2b((v.w - m) * r * gv.w + bv.w);
  *(ushort4*)(out + (size_t)row * kD + tid * 4) = o;
}

// ------------- transpose + fp32->bf16:  out[c][r] = in[r][c] -------------
__global__ __launch_bounds__(256)
void transpose_cvt(const float* __restrict__ in, u16* __restrict__ out, int R, int C) {
  __shared__ float tile[32][33];
  const int c0 = blockIdx.x * 32, r0 = blockIdx.y * 32;
  const int x = threadIdx.x, y = threadIdx.y;
#pragma unroll
  for (int i = 0; i < 4; ++i)
    tile[y + i * 8][x] = in[(size_t)(r0 + y + i * 8) * C + c0 + x];
  __syncthreads();
#pragma unroll
  for (int i = 0; i < 4; ++i)
    out[(size_t)(c0 + y + i * 8) * R + r0 + x] = f2b(tile[x][y + i * 8]);
}

__global__ void concat_bias(const float* __restrict__ bq, const float* __restrict__ bk,
                            const float* __restrict__ bv, float* __restrict__ out) {
  int i = blockIdx.x * 256 + threadIdx.x;  // 3072
  out[i] = i < kD ? bq[i] : (i < 2 * kD ? bk[i - kD] : bv[i - 2 * kD]);
}

// --- per-head V transpose: qkv[s][2048+h*64+d] (bf16) -> vt[h][d][s] (bf16) ---
__global__ __launch_bounds__(256)
void vtrans(const u16* __restrict__ qkv, u16* __restrict__ vt) {
  __shared__ u16 t[64][72];
  const int s0 = blockIdx.x * 64, h = blockIdx.y, tid = threadIdx.x;
#pragma unroll
  for (int r = 0; r < 2; ++r) {
    int chunk = r * 256 + tid, row = chunk >> 3, col = (chunk & 7) * 8;
    uint4 v = *(const uint4*)(qkv + (size_t)(s0 + row) * 3072 + 2 * kD + h * 64 + col);
    *(uint4*)(&t[row][col]) = v;
  }
  __syncthreads();
#pragma unroll
  for (int r = 0; r < 2; ++r) {
    int chunk = r * 256 + tid, drow = chunk >> 3, scol = (chunk & 7) * 8;
    u16 tmp[8];
#pragma unroll
    for (int j = 0; j < 8; ++j) tmp[j] = t[scol + j][drow];
    *(uint4*)(vt + (size_t)h * 64 * kS + (size_t)drow * kS + s0 + scol) = *(uint4*)tmp;
  }
}

// ---------------- bt-GEMM: C[M,N] = A[M,K](bf16) x Bt[N,K](bf16) ----------------
// 128x128 tile, BK=32, 4 waves, 16 MFMA/K-iter, XOR-swizzled LDS.
// DOUBLE-BUFFERED staging: stage tile t+1 -> s_waitcnt vmcnt(4) (tile t's 4 DMAs
// done; next tile's stay in flight) -> s_barrier -> ds_read+MFMA -> s_barrier.
// EPI 0: bf16 out (+bias)   EPI 1: bf16 gelu_erf out (+bias)
// EPI 3: fp32 partial store (split-K via blockIdx.z; no bias)
template <int EPI>
__global__ __launch_bounds__(256, 2)
void gemm_bt(const u16* __restrict__ A, const u16* __restrict__ Bt,
             const float* __restrict__ bias, void* __restrict__ Cout,
             int N, int K, int Ksub) {
  constexpr int BM = 128, BN = 128, BK = 32;
  constexpr int MT = 4, NT = 4;              // 16x16 tiles per wave
  __shared__ u16 As[2][BM * BK];
  __shared__ u16 Bs[2][BN * BK];
  const int tid = threadIdx.x;
  const int w = tid >> 6, l = tid & 63;
  const int wm = w >> 1, wn = w & 1;
  const int row0 = blockIdx.y * BM, col0 = blockIdx.x * BN;
  const int koff = blockIdx.z * Ksub;

  // staging: lane l stages (row = w*16 + l/4, chunk = l&3); LDS slot's chunk is
  // XOR-swizzled, so the global source chunk is (l&3) ^ ((l>>3)&3).
  const int sc = ((l & 3) ^ ((l >> 3) & 3)) * 8;
  const u16* Ag = A + (size_t)(row0 + w * 16 + (l >> 2)) * K + koff + sc;
  const u16* Bg = Bt + (size_t)(col0 + w * 16 + (l >> 2)) * K + koff + sc;

  f32x4 acc[MT][NT] = {};
  const int q = l >> 4;                      // k-chunk this lane reads for MFMA
  const int nIter = Ksub / BK;

  // prologue: stage tile 0 into buffer 0
#pragma unroll
  for (int r = 0; r < 2; ++r) async16(Ag, &As[0][w * 512 + r * 2048]), Ag += (size_t)64 * K * 0;
  // (written explicitly below to keep address math simple)
  // -- the line above intentionally stages only once; redo properly:
#pragma unroll
  for (int r = 1; r < 2; ++r) {}
  {
    async16(Ag + (size_t)64 * K, &As[0][w * 512 + 2048]);
    async16(Bg, &Bs[0][w * 512]);
    async16(Bg + (size_t)64 * K, &Bs[0][w * 512 + 2048]);
  }

  for (int t = 0; t < nIter; ++t) {
    const int cur = t & 1;
    if (t + 1 < nIter) {
      const int kt = (t + 1) * BK;
      async16(Ag + kt, &As[cur ^ 1][w * 512]);
      async16(Ag + (size_t)64 * K + kt, &As[cur ^ 1][w * 512 + 2048]);
      async16(Bg + kt, &Bs[cur ^ 1][w * 512]);
      async16(Bg + (size_t)64 * K + kt, &Bs[cur ^ 1][w * 512 + 2048]);
      asm volatile("s_waitcnt vmcnt(4)" ::: "memory");  // tile t's 4 DMAs done
    } else {
      asm volatile("s_waitcnt vmcnt(0)" ::: "memory");
    }
    __builtin_amdgcn_s_barrier();            // all waves' tile-t DMAs visible
    __builtin_amdgcn_sched_barrier(0);       // keep ds_reads below the wait
    const u16* Asc = As[cur];
    const u16* Bsc = Bs[cur];
    bf16x8 af[MT], bfr[NT];
#pragma unroll
    for (int i = 0; i < MT; ++i) {
      const int ra = wm * 64 + i * 16 + (l & 15);
      af[i] = *(const bf16x8*)(Asc + ra * 32 + (q ^ ((ra >> 1) & 3)) * 8);
    }
#pragma unroll
    for (int j = 0; j < NT; ++j) {
      const int rb = wn * 64 + j * 16 + (l & 15);
      bfr[j] = *(const bf16x8*)(Bsc + rb * 32 + (q ^ ((rb >> 1) & 3)) * 8);
    }
#pragma unroll
    for (int i = 0; i < MT; ++i)
#pragma unroll
      for (int j = 0; j < NT; ++j)
        acc[i][j] = __builtin_amdgcn_mfma_f32_16x16x32_bf16(af[i], bfr[j], acc[i][j], 0, 0, 0);
    __builtin_amdgcn_s_barrier();            // all done reading buf[cur] before restage
  }

  float* Pf = nullptr;
  if constexpr (EPI == 3)
    Pf = (float*)Cout + (size_t)blockIdx.z * gridDim.y * BM * N;
#pragma unroll
  for (int i = 0; i < MT; ++i) {
    const int row = row0 + wm * 64 + i * 16 + ((l >> 4) << 2);
#pragma unroll
    for (int j = 0; j < NT; ++j) {
      const int col = col0 + wn * 64 + j * 16 + (l & 15);
      float bb = 0.f;
      if constexpr (EPI != 3) bb = bias[col];
#pragma unroll
      for (int r = 0; r < 4; ++r) {
        const size_t idx = (size_t)(row + r) * N + col;
        float v = acc[i][j][r] + bb;
        if constexpr (EPI == 0) {
          ((u16*)Cout)[idx] = f2b(v);
        } else if constexpr (EPI == 1) {
          ((u16*)Cout)[idx] = f2b(0.5f * v * (1.f + erff(v * 0.7071067811865475f)));
        } else {
          Pf[idx] = v;
        }
      }
    }
  }
}

// ---- split-K reduce: out = sum_s parts[s] + bias + res  (fp32, float4) ----
template <int KS>
__global__ __launch_bounds__(256)
void reduce_add(const float* __restrict__ parts, const float* __restrict__ bias,
                const float* __restrict__ res, float* __restrict__ out,
                int N, size_t strideMN) {
  const size_t b = ((size_t)blockIdx.x * 256 + threadIdx.x) * 4;
  float4 a = *(const float4*)(res + b);
  const float4 bv = *(const float4*)(bias + (b & (size_t)(N - 1)));
  a.x += bv.x; a.y += bv.y; a.z += bv.z; a.w += bv.w;
#pragma unroll
  for (int s = 0; s < KS; ++s) {
    const float4 p = *(const float4*)(parts + s * strideMN + b);
    a.x += p.x; a.y += p.y; a.z += p.z; a.w += p.w;
  }
  *(float4*)(out + b) = a;
}

// ---------------- flash attention (swapped QK^T, 16x16x32) ----------------
// grid (S/64, H), 256 thr (4 waves); wave w owns q-rows [q0+w*16, +16).
// S^T = mfma(K, Q): D[k_local][q], col = lane&15 = q -> softmax is LANE-LOCAL.
// P packed 4-at-a-time (uint2) into the verified Ps[q][s] layout; T14: next
// tile's global loads are issued right after the stage barrier.
__global__ __launch_bounds__(256, 2)
void flash_attn(const u16* __restrict__ qkv, const u16* __restrict__ vt,
                u16* __restrict__ og) {
  constexpr int LQ = 72;    // 64 + 8 pad (breaks b128 bank conflicts)
  constexpr int LV = 136;   // 128 + 8 pad
  __shared__ u16 Qs[64 * LQ];
  __shared__ u16 Ks[128 * LQ];
  __shared__ u16 Vs[64 * LV];       // V^T tile: [d][s]
  __shared__ u16 Ps[4][16 * LV];    // per-wave P[q][s]
  const int tid = threadIdx.x, w = tid >> 6, l = tid & 63;
  const int t4 = l >> 4, ln = l & 15;
  const int h = blockIdx.y, q0 = blockIdx.x * 64;

  // stage Q [64][64]
#pragma unroll
  for (int r = 0; r < 2; ++r) {
    int chunk = r * 256 + tid, row = chunk >> 3, col = (chunk & 7) * 8;
    uint4 v = *(const uint4*)(qkv + (size_t)(q0 + row) * 3072 + h * 64 + col);
    *(uint4*)(&Qs[row * LQ + col]) = v;
  }
  // prologue: issue tile-0 K/V loads into registers
  uint4 kreg[4], vreg[4];
#pragma unroll
  for (int r = 0; r < 4; ++r) {
    int chunk = r * 256 + tid, row = chunk >> 3, col = (chunk & 7) * 8;
    kreg[r] = *(const uint4*)(qkv + (size_t)row * 3072 + kD + h * 64 + col);
  }
#pragma unroll
  for (int r = 0; r < 4; ++r) {
    int chunk = r * 256 + tid, row = chunk >> 4, col = (chunk & 15) * 8;
    vreg[r] = *(const uint4*)(vt + (size_t)h * 64 * kS + (size_t)row * kS + col);
  }
  __syncthreads();   // Qs visible
  bf16x8 qa[2];
#pragma unroll
  for (int kq = 0; kq < 2; ++kq)
    qa[kq] = *(const bf16x8*)(&Qs[(w * 16 + ln) * LQ + kq * 32 + t4 * 8]);

  f32x4 oacc[4] = {};
  float mi = -1e30f, li = 0.f;

  for (int kt = 0; kt < kS; kt += 128) {
    // ---- store staged registers -> LDS (K-tile [128][64], V^T tile [64][128]) ----
#pragma unroll
    for (int r = 0; r < 4; ++r) {
      int chunk = r * 256 + tid, row = chunk >> 3, col = (chunk & 7) * 8;
      *(uint4*)(&Ks[row * LQ + col]) = kreg[r];
    }
#pragma unroll
    for (int r = 0; r < 4; ++r) {
      int chunk = r * 256 + tid, row = chunk >> 4, col = (chunk & 15) * 8;
      *(uint4*)(&Vs[row * LV + col]) = vreg[r];
    }
    __syncthreads();  // tile kt visible to all waves
    // ---- T14: issue next tile's loads; they complete under compute ----
    if (kt + 128 < kS) {
#pragma unroll
      for (int r = 0; r < 4; ++r) {
        int chunk = r * 256 + tid, row = chunk >> 3, col = (chunk & 7) * 8;
        kreg[r] = *(const uint4*)(qkv + (size_t)(kt + 128 + row) * 3072 + kD + h * 64 + col);
      }
#pragma unroll
      for (int r = 0; r < 4; ++r) {
        int chunk = r * 256 + tid, row = chunk >> 4, col = (chunk & 15) * 8;
        vreg[r] = *(const uint4*)(vt + (size_t)h * 64 * kS + (size_t)row * kS + kt + 128 + col);
      }
    }

    // ---- S^T = K Q^T : st[n] = D[k_local][q], k = 16n + 4*t4 + r, q = ln ----
    f32x4 st[8];
#pragma unroll
    for (int n = 0; n < 8; ++n) {
      f32x4 z = {};
      bf16x8 kb0 = *(const bf16x8*)(&Ks[(n * 16 + ln) * LQ + t4 * 8]);
      bf16x8 kb1 = *(const bf16x8*)(&Ks[(n * 16 + ln) * LQ + 32 + t4 * 8]);
      z = __builtin_amdgcn_mfma_f32_16x16x32_bf16(kb0, qa[0], z, 0, 0, 0);
      z = __builtin_amdgcn_mfma_f32_16x16x32_bf16(kb1, qa[1], z, 0, 0, 0);
      st[n] = z;
    }
    // ---- lane-local online softmax (q = ln; quads combined via xor 16/32) ----
    float pm = -1e30f;
#pragma unroll
    for (int n = 0; n < 8; ++n) {
      float m01 = fmaxf(st[n][0], st[n][1]);
      float m23 = fmaxf(st[n][2], st[n][3]);
      pm = fmaxf(pm, fmaxf(m01, m23));
    }
    pm = fmaxf(pm, __shfl_xor(pm, 16));
    pm = fmaxf(pm, __shfl_xor(pm, 32));
    pm *= 0.125f;  // 1/sqrt(DK); positive scale commutes with max
    const float mn = fmaxf(mi, pm);
    const float al = __expf(mi - mn);
    mi = mn;
    li *= al;
    float ar[4];
#pragma unroll
    for (int r = 0; r < 4; ++r) ar[r] = __shfl(al, t4 * 4 + r);  // alpha by q-row
#pragma unroll
    for (int n = 0; n < 4; ++n)
#pragma unroll
      for (int r = 0; r < 4; ++r) oacc[n][r] *= ar[r];
    // ---- P = exp(s*0.125 - mi); pack r-quad -> uint2 (k co-increments with r) ----
    float ls = 0.f;
#pragma unroll
    for (int n = 0; n < 8; ++n) {
      float p0 = __expf(st[n][0] * 0.125f - mi);
      float p1 = __expf(st[n][1] * 0.125f - mi);
      float p2 = __expf(st[n][2] * 0.125f - mi);
      float p3 = __expf(st[n][3] * 0.125f - mi);
      ls += (p0 + p1) + (p2 + p3);
      uint2 pk;
      pk.x = (u32)f2b(p0) | ((u32)f2b(p1) << 16);
      pk.y = (u32)f2b(p2) | ((u32)f2b(p3) << 16);
      *(uint2*)(&Ps[w][ln * LV + n * 16 + t4 * 4]) = pk;  // P[q=ln][k..k+3]
    }
    ls += __shfl_xor(ls, 16);
    ls += __shfl_xor(ls, 32);
    li += ls;
    // ---- O += P V   (P 16x128 from own-wave LDS region; V^T in Vs) ----
    bf16x8 pa[4];
#pragma unroll
    for (int ks = 0; ks < 4; ++ks)
      pa[ks] = *(const bf16x8*)(&Ps[w][ln * LV + ks * 32 + t4 * 8]);
#pragma unroll
    for (int n = 0; n < 4; ++n)
#pragma unroll
      for (int ks = 0; ks < 4; ++ks) {
        bf16x8 vb = *(const bf16x8*)(&Vs[(n * 16 + ln) * LV + ks * 32 + t4 * 8]);
        oacc[n] = __builtin_amdgcn_mfma_f32_16x16x32_bf16(pa[ks], vb, oacc[n], 0, 0, 0);
      }
    __syncthreads();   // all waves done reading Ks/Vs before next store
  }
  // epilogue: normalize, write og[h][s][d] (contiguous == reference reshape)
#pragma unroll
  for (int r = 0; r < 4; ++r) {
    float lr = __shfl(li, t4 * 4 + r);
    float inv = 1.f / lr;
    int srow = q0 + w * 16 + t4 * 4 + r;
#pragma unroll
    for (int n = 0; n < 4; ++n) {
      int d = n * 16 + ln;
      og[(size_t)h * kS * kDK + (size_t)srow * kDK + d] = f2b(oacc[n][r] * inv);
    }
  }
}

extern "C" void kernel_launch(void* const* d_in, const int* in_sizes, int n_in,
                              void* d_out, int out_size, void* d_ws, size_t ws_size,
                              hipStream_t stream) {
  const float* x = (const float*)d_in[0];
  const float* wq = (const float*)d_in[1];
  const float* bq = (const float*)d_in[2];
  const float* wk = (const float*)d_in[3];
  const float* bk = (const float*)d_in[4];
  const float* wv = (const float*)d_in[5];
  const float* bv = (const float*)d_in[6];
  const float* wo = (const float*)d_in[7];
  const float* bo = (const float*)d_in[8];
  const float* w1 = (const float*)d_in[9];
  const float* b1 = (const float*)d_in[10];
  const float* w2 = (const float*)d_in[11];
  const float* b2 = (const float*)d_in[12];
  const float* ln1g = (const float*)d_in[13];
  const float* ln1b = (const float*)d_in[14];
  const float* ln2g = (const float*)d_in[15];
  const float* ln2b = (const float*)d_in[16];
  float* out = (float*)d_out;

  // Workspace plan. "pool" buffers are all dead by the time the split-K
  // partials are written, so partials alias pool base.
  char* p = (char*)d_ws;
  auto alloc = [&](size_t bytes) { void* q = (void*)p; p += (bytes + 255) & ~(size_t)255; return q; };
  u16* h1 = (u16*)alloc((size_t)kS * kD * 2);
  u16* wqkvt = (u16*)alloc((size_t)3 * kD * kD * 2);
  u16* qkv = (u16*)alloc((size_t)kS * 3 * kD * 2);
  u16* vt = (u16*)alloc((size_t)kH * kDK * kS * 2);
  u16* og = (u16*)alloc((size_t)kS * kD * 2);
  u16* wot = (u16*)alloc((size_t)kD * kD * 2);
  u16* h2 = (u16*)alloc((size_t)kS * kD * 2);
  u16* w1t = (u16*)alloc((size_t)kD * kMLP * 2);
  float* bqkv = (float*)alloc((size_t)3 * kD * 4);
  float* x2 = (float*)alloc((size_t)kS * kD * 4);
  u16* fbuf = (u16*)alloc((size_t)kS * kMLP * 2);
  u16* w2t = (u16*)alloc((size_t)kMLP * kD * 2);
  float* part = (float*)d_ws;  // aliases pool (see plan above)
  const size_t strideMN = (size_t)kS * kD;

  dim3 tb(32, 8);
  transpose_cvt<<<dim3(kD / 32, kD / 32), tb, 0, stream>>>(wq, wqkvt, kD, kD);
  transpose_cvt<<<dim3(kD / 32, kD / 32), tb, 0, stream>>>(wk, wqkvt + kD * kD, kD, kD);
  transpose_cvt<<<dim3(kD / 32, kD / 32), tb, 0, stream>>>(wv, wqkvt + 2 * kD * kD, kD, kD);
  transpose_cvt<<<dim3(kD / 32, kD / 32), tb, 0, stream>>>(wo, wot, kD, kD);
  transpose_cvt<<<dim3(kMLP / 32, kD / 32), tb, 0, stream>>>(w1, w1t, kD, kMLP);
  transpose_cvt<<<dim3(kD / 32, kMLP / 32), tb, 0, stream>>>(w2, w2t, kMLP, kD);
  concat_bias<<<dim3(12), dim3(256), 0, stream>>>(bq, bk, bv, bqkv);

  ln_kernel<<<dim3(kS), dim3(256), 0, stream>>>(x, ln1g, ln1b, h1);
  // fused QKV: [2048,1024] x [3072,1024]^T -> qkv bf16 [2048,3072]
  gemm_bt<0><<<dim3(3 * kD / 128, kS / 128, 1), dim3(256), 0, stream>>>(
      h1, wqkvt, bqkv, qkv, 3 * kD, kD, kD);
  vtrans<<<dim3(kS / 64, kH), dim3(256), 0, stream>>>(qkv, vt);
  flash_attn<<<dim3(kS / 64, kH), dim3(256), 0, stream>>>(qkv, vt, og);
  // O-proj split-K=2: partials = og @ wo  (fp32)
  gemm_bt<3><<<dim3(kD / 128, kS / 128, 2), dim3(256), 0, stream>>>(
      og, wot, nullptr, part, kD, kD, kD / 2);
  // x2 = x + part0 + part1 + bo
  reduce_add<2><<<dim3(kS * kD / 4 / 256), dim3(256), 0, stream>>>(
      part, bo, x, x2, kD, strideMN);
  ln_kernel<<<dim3(kS), dim3(256), 0, stream>>>(x2, ln2g, ln2b, h2);
  // FFN1 + exact GELU -> bf16 [2048,4096]
  gemm_bt<1><<<dim3(kMLP / 128, kS / 128, 1), dim3(256), 0, stream>>>(
      h2, w1t, b1, fbuf, kMLP, kD, kD);
  // FFN2 split-K=4: partials = gelu @ w2  (fp32)
  gemm_bt<3><<<dim3(kD / 128, kS / 128, 4), dim3(256), 0, stream>>>(
      fbuf, w2t, nullptr, part, kD, kMLP, kMLP / 4);
  // out = x2 + sum(parts) + b2
  reduce_add<4><<<dim3(kS * kD / 4 / 256), dim3(256), 0, stream>>>(
      part, b2, x2, out, kD, strideMN);
}

// Round 4
// 322.491 us; speedup vs baseline: 1.0353x; 1.0277x over previous
//
#include <hip/hip_runtime.h>

// EncoderBlock: pre-LN MHSA + pre-LN GELU FFN.  S=2048 D=1024 H=16 DK=64 MLP=4096.
// GEMMs: bf16 MFMA 16x16x32, bt-GEMM (A[M,K] x Bt[N,K]), 128x64 tile (4 waves,
// BM=128 BN=64 BK=32), XOR-swizzled LDS, double-buffered global_load_lds staging
// with counted s_waitcnt vmcnt(3) + raw s_barrier.  Small-N tiles raise grid to
// 3-4 blocks/CU (m102: block-level overlap, not intra-block pipelining, is what
// fills the MFMA pipe at these shapes).  N=1024 GEMMs use split-K + fused reduce.
// Attention: round-0 proven flash kernel (66.5 us measured).

constexpr int kS = 2048, kD = 1024, kH = 16, kDK = 64, kMLP = 4096;
constexpr float kEps = 1e-5f;

using u16 = unsigned short;
using u32 = unsigned int;
typedef float f32x4 __attribute__((ext_vector_type(4)));
typedef short bf16x8 __attribute__((ext_vector_type(8)));   // 8 bf16 = 4 VGPRs

__device__ __forceinline__ u16 f2b(float f) {               // fp32 -> bf16 (RNE)
  u32 u = __builtin_bit_cast(u32, f);
  return (u16)((u + 0x7fffu + ((u >> 16) & 1u)) >> 16);
}

typedef const __attribute__((address_space(1))) u32* gas1;
typedef __attribute__((address_space(3))) u32* las3;
__device__ __forceinline__ void async16(const void* g, void* l) {
  // global -> LDS DMA, 16B/lane; LDS dest = wave-uniform base + lane*16
  __builtin_amdgcn_global_load_lds((gas1)g, (las3)l, 16, 0, 0);
}

// ---------------- LayerNorm: fp32 [row][1024] -> bf16 ----------------
__global__ __launch_bounds__(256)
void ln_kernel(const float* __restrict__ x, const float* __restrict__ g,
               const float* __restrict__ b, u16* __restrict__ out) {
  __shared__ float red[8];
  const int row = blockIdx.x, tid = threadIdx.x;
  const float4 v = *(const float4*)(x + (size_t)row * kD + tid * 4);
  float s = v.x + v.y + v.z + v.w;
  float ss = v.x * v.x + v.y * v.y + v.z * v.z + v.w * v.w;
#pragma unroll
  for (int d = 1; d < 64; d <<= 1) { s += __shfl_xor(s, d); ss += __shfl_xor(ss, d); }
  if ((tid & 63) == 0) { red[tid >> 6] = s; red[4 + (tid >> 6)] = ss; }
  __syncthreads();
  const float m = (red[0] + red[1] + red[2] + red[3]) * (1.f / kD);
  const float var = (red[4] + red[5] + red[6] + red[7]) * (1.f / kD) - m * m;
  const float r = rsqrtf(var + kEps);
  const float4 gv = *(const float4*)(g + tid * 4);
  const float4 bv = *(const float4*)(b + tid * 4);
  ushort4 o;
  o.x = f2b((v.x - m) * r * gv.x + bv.x);
  o.y = f2b((v.y - m) * r * gv.y + bv.y);
  o.z = f2b((v.z - m) * r * gv.z + bv.z);
  o.w = f2b((v.w - m) * r * gv.w + bv.w);
  *(ushort4*)(out + (size_t)row * kD + tid * 4) = o;
}

// ------------- transpose + fp32->bf16:  out[c][r] = in[r][c] -------------
__global__ __launch_bounds__(256)
void transpose_cvt(const float* __restrict__ in, u16* __restrict__ out, int R, int C) {
  __shared__ float tile[32][33];
  const int c0 = blockIdx.x * 32, r0 = blockIdx.y * 32;
  const int x = threadIdx.x, y = threadIdx.y;
#pragma unroll
  for (int i = 0; i < 4; ++i)
    tile[y + i * 8][x] = in[(size_t)(r0 + y + i * 8) * C + c0 + x];
  __syncthreads();
#pragma unroll
  for (int i = 0; i < 4; ++i)
    out[(size_t)(c0 + y + i * 8) * R + r0 + x] = f2b(tile[x][y + i * 8]);
}

__global__ void concat_bias(const float* __restrict__ bq, const float* __restrict__ bk,
                            const float* __restrict__ bv, float* __restrict__ out) {
  int i = blockIdx.x * 256 + threadIdx.x;  // 3072
  out[i] = i < kD ? bq[i] : (i < 2 * kD ? bk[i - kD] : bv[i - 2 * kD]);
}

// --- per-head V transpose: qkv[s][2048+h*64+d] (bf16) -> vt[h][d][s] (bf16) ---
__global__ __launch_bounds__(256)
void vtrans(const u16* __restrict__ qkv, u16* __restrict__ vt) {
  __shared__ u16 t[64][72];
  const int s0 = blockIdx.x * 64, h = blockIdx.y, tid = threadIdx.x;
#pragma unroll
  for (int r = 0; r < 2; ++r) {
    int chunk = r * 256 + tid, row = chunk >> 3, col = (chunk & 7) * 8;
    uint4 v = *(const uint4*)(qkv + (size_t)(s0 + row) * 3072 + 2 * kD + h * 64 + col);
    *(uint4*)(&t[row][col]) = v;
  }
  __syncthreads();
#pragma unroll
  for (int r = 0; r < 2; ++r) {
    int chunk = r * 256 + tid, drow = chunk >> 3, scol = (chunk & 7) * 8;
    u16 tmp[8];
#pragma unroll
    for (int j = 0; j < 8; ++j) tmp[j] = t[scol + j][drow];
    *(uint4*)(vt + (size_t)h * 64 * kS + (size_t)drow * kS + s0 + scol) = *(uint4*)tmp;
  }
}

// ---------------- bt-GEMM: C[M,N] = A[M,K](bf16) x Bt[N,K](bf16) ----------------
// 128x64 tile, BK=32, 4 waves (each owns 32 M-rows x 64 N-cols), 8 MFMA/K-iter,
// XOR-swizzled LDS, double-buffered staging, counted s_waitcnt vmcnt(3).
// Small BN -> grids of 512-1024 blocks = 2-4 blocks/CU for inter-block overlap.
// EPI 0: bf16 out (+bias)   EPI 1: bf16 gelu_erf out (+bias)
// EPI 3: fp32 partial store (split-K via blockIdx.z; no bias)
template <int EPI>
__global__ __launch_bounds__(256, 4)
void gemm_bt(const u16* __restrict__ A, const u16* __restrict__ Bt,
             const float* __restrict__ bias, void* __restrict__ Cout,
             int N, int K, int Ksub) {
  constexpr int BM = 128, BN = 64, BK = 32;
  constexpr int MT = 2, NT = 4;              // 16x16 tiles per wave
  __shared__ u16 As[2][BM * BK];             // 8 KB per buffer
  __shared__ u16 Bs[2][BN * BK];             // 4 KB per buffer
  const int tid = threadIdx.x;
  const int w = tid >> 6, l = tid & 63;
  const int row0 = blockIdx.y * BM, col0 = blockIdx.x * BN;
  const int koff = blockIdx.z * Ksub;

  // staging: lane l stages (row = base + l/4, chunk = l&3); LDS slot's chunk is
  // XOR-swizzled, so the global source chunk is (l&3) ^ ((row>>1)&3) = (l&3)^((l>>3)&3)
  // (row bases are multiples of 16, so the swizzle term depends only on l).
  const int sc = ((l & 3) ^ ((l >> 3) & 3)) * 8;
  const u16* Ag = A + (size_t)(row0 + w * 32 + (l >> 2)) * K + koff + sc;
  const u16* Bg = Bt + (size_t)(col0 + w * 16 + (l >> 2)) * K + koff + sc;

  f32x4 acc[MT][NT] = {};
  const int q = l >> 4;                      // k-chunk this lane reads for MFMA
  const int nIter = Ksub / BK;

  // prologue: stage tile 0 into buffer 0 (wave w: A rows w*32..+32, B rows w*16..+16)
  async16(Ag, &As[0][w * 1024]);
  async16(Ag + (size_t)16 * K, &As[0][w * 1024 + 512]);
  async16(Bg, &Bs[0][w * 512]);

  for (int t = 0; t < nIter; ++t) {
    const int cur = t & 1;
    if (t + 1 < nIter) {
      const int kt = (t + 1) * BK;
      async16(Ag + kt, &As[cur ^ 1][w * 1024]);
      async16(Ag + (size_t)16 * K + kt, &As[cur ^ 1][w * 1024 + 512]);
      async16(Bg + kt, &Bs[cur ^ 1][w * 512]);
      asm volatile("s_waitcnt vmcnt(3)" ::: "memory");  // tile t's 3 DMAs done
    } else {
      asm volatile("s_waitcnt vmcnt(0)" ::: "memory");
    }
    __builtin_amdgcn_s_barrier();            // all waves' tile-t DMAs visible
    __builtin_amdgcn_sched_barrier(0);       // keep ds_reads below the wait
    const u16* Asc = As[cur];
    const u16* Bsc = Bs[cur];
    bf16x8 af[MT], bfr[NT];
#pragma unroll
    for (int i = 0; i < MT; ++i) {
      const int ra = w * 32 + i * 16 + (l & 15);
      af[i] = *(const bf16x8*)(Asc + ra * 32 + (q ^ ((ra >> 1) & 3)) * 8);
    }
#pragma unroll
    for (int j = 0; j < NT; ++j) {
      const int rb = j * 16 + (l & 15);
      bfr[j] = *(const bf16x8*)(Bsc + rb * 32 + (q ^ ((rb >> 1) & 3)) * 8);
    }
#pragma unroll
    for (int i = 0; i < MT; ++i)
#pragma unroll
      for (int j = 0; j < NT; ++j)
        acc[i][j] = __builtin_amdgcn_mfma_f32_16x16x32_bf16(af[i], bfr[j], acc[i][j], 0, 0, 0);
    __builtin_amdgcn_s_barrier();            // all done reading buf[cur] before restage
  }

  float* Pf = nullptr;
  if constexpr (EPI == 3)
    Pf = (float*)Cout + (size_t)blockIdx.z * gridDim.y * BM * N;
#pragma unroll
  for (int i = 0; i < MT; ++i) {
    const int row = row0 + w * 32 + i * 16 + ((l >> 4) << 2);
#pragma unroll
    for (int j = 0; j < NT; ++j) {
      const int col = col0 + j * 16 + (l & 15);
      float bb = 0.f;
      if constexpr (EPI != 3) bb = bias[col];
#pragma unroll
      for (int r = 0; r < 4; ++r) {
        const size_t idx = (size_t)(row + r) * N + col;
        float v = acc[i][j][r] + bb;
        if constexpr (EPI == 0) {
          ((u16*)Cout)[idx] = f2b(v);
        } else if constexpr (EPI == 1) {
          ((u16*)Cout)[idx] = f2b(0.5f * v * (1.f + erff(v * 0.7071067811865475f)));
        } else {
          Pf[idx] = v;
        }
      }
    }
  }
}

// ---- split-K reduce: out = sum_s parts[s] + bias + res  (fp32, float4) ----
template <int KS>
__global__ __launch_bounds__(256)
void reduce_add(const float* __restrict__ parts, const float* __restrict__ bias,
                const float* __restrict__ res, float* __restrict__ out,
                int N, size_t strideMN) {
  const size_t b = ((size_t)blockIdx.x * 256 + threadIdx.x) * 4;
  float4 a = *(const float4*)(res + b);
  const float4 bv = *(const float4*)(bias + (b & (size_t)(N - 1)));
  a.x += bv.x; a.y += bv.y; a.z += bv.z; a.w += bv.w;
#pragma unroll
  for (int s = 0; s < KS; ++s) {
    const float4 p = *(const float4*)(parts + s * strideMN + b);
    a.x += p.x; a.y += p.y; a.z += p.z; a.w += p.w;
  }
  *(float4*)(out + b) = a;
}

// ---------------- flash attention (round-0 proven version) ----------------
// grid (S/64, H), 256 thr (4 waves); wave w owns q-rows [q0+w*16, +16).
__global__ __launch_bounds__(256, 2)
void flash_attn(const u16* __restrict__ qkv, const u16* __restrict__ vt,
                u16* __restrict__ og) {
  constexpr int LQ = 72;    // 64 + 8 pad (breaks b128 bank conflicts)
  constexpr int LV = 136;   // 128 + 8 pad
  __shared__ u16 Qs[64 * LQ];
  __shared__ u16 Ks[128 * LQ];
  __shared__ u16 Vs[64 * LV];       // V^T tile: [d][s]
  __shared__ u16 Ps[4][16 * LV];    // per-wave P (C-layout -> A-layout round trip)
  const int tid = threadIdx.x, w = tid >> 6, l = tid & 63;
  const int h = blockIdx.y, q0 = blockIdx.x * 64;

  // stage Q [64][64]
#pragma unroll
  for (int r = 0; r < 2; ++r) {
    int chunk = r * 256 + tid, row = chunk >> 3, col = (chunk & 7) * 8;
    uint4 v = *(const uint4*)(qkv + (size_t)(q0 + row) * 3072 + h * 64 + col);
    *(uint4*)(&Qs[row * LQ + col]) = v;
  }
  __syncthreads();
  bf16x8 qa[2];
#pragma unroll
  for (int kq = 0; kq < 2; ++kq)
    qa[kq] = *(const bf16x8*)(&Qs[(w * 16 + (l & 15)) * LQ + kq * 32 + (l >> 4) * 8]);

  f32x4 oacc[4] = {};
  float mi[4], li[4];
#pragma unroll
  for (int r = 0; r < 4; ++r) { mi[r] = -1e30f; li[r] = 0.f; }

  for (int kt = 0; kt < kS; kt += 128) {
    __syncthreads();  // prev iter done reading Ks/Vs
    // stage K-tile [128][64]
#pragma unroll
    for (int r = 0; r < 4; ++r) {
      int chunk = r * 256 + tid, row = chunk >> 3, col = (chunk & 7) * 8;
      uint4 v = *(const uint4*)(qkv + (size_t)(kt + row) * 3072 + kD + h * 64 + col);
      *(uint4*)(&Ks[row * LQ + col]) = v;
    }
    // stage V^T tile [64][128]
#pragma unroll
    for (int r = 0; r < 4; ++r) {
      int chunk = r * 256 + tid, row = chunk >> 4, col = (chunk & 15) * 8;
      uint4 v = *(const uint4*)(vt + (size_t)h * 64 * kS + (size_t)row * kS + kt + col);
      *(uint4*)(&Vs[row * LV + col]) = v;
    }
    __syncthreads();

    // S = Q K^T  (16 q-rows x 128 cols per wave)
    f32x4 s[8];
#pragma unroll
    for (int n = 0; n < 8; ++n) {
      f32x4 z = {};
      bf16x8 kb0 = *(const bf16x8*)(&Ks[(n * 16 + (l & 15)) * LQ + (l >> 4) * 8]);
      bf16x8 kb1 = *(const bf16x8*)(&Ks[(n * 16 + (l & 15)) * LQ + 32 + (l >> 4) * 8]);
      z = __builtin_amdgcn_mfma_f32_16x16x32_bf16(qa[0], kb0, z, 0, 0, 0);
      z = __builtin_amdgcn_mfma_f32_16x16x32_bf16(qa[1], kb1, z, 0, 0, 0);
      s[n] = z;
    }
    // online softmax (rows live on 16 lanes sharing l>>4; cols = l&15 across 8 frags)
    float alpha[4];
#pragma unroll
    for (int r = 0; r < 4; ++r) {
      float m = -1e30f;
#pragma unroll
      for (int n = 0; n < 8; ++n) m = fmaxf(m, s[n][r]);
#pragma unroll
      for (int d = 1; d < 16; d <<= 1) m = fmaxf(m, __shfl_xor(m, d));
      m *= 0.125f;  // 1/sqrt(DK); positive scale commutes with max
      float mn = fmaxf(mi[r], m);
      alpha[r] = __expf(mi[r] - mn);
      mi[r] = mn;
      li[r] *= alpha[r];
    }
#pragma unroll
    for (int n = 0; n < 4; ++n)
#pragma unroll
      for (int r = 0; r < 4; ++r) oacc[n][r] *= alpha[r];
    float rs[4] = {0.f, 0.f, 0.f, 0.f};
#pragma unroll
    for (int n = 0; n < 8; ++n)
#pragma unroll
      for (int r = 0; r < 4; ++r) {
        float pv = __expf(s[n][r] * 0.125f - mi[r]);
        rs[r] += pv;
        Ps[w][((l >> 4) * 4 + r) * LV + n * 16 + (l & 15)] = f2b(pv);
      }
#pragma unroll
    for (int r = 0; r < 4; ++r) {
      float t = rs[r];
#pragma unroll
      for (int d = 1; d < 16; d <<= 1) t += __shfl_xor(t, d);
      li[r] += t;
    }
    // O += P V   (P 16x128 from own-wave LDS region; V^T in Vs)
    bf16x8 pa[4];
#pragma unroll
    for (int ks = 0; ks < 4; ++ks)
      pa[ks] = *(const bf16x8*)(&Ps[w][(l & 15) * LV + ks * 32 + (l >> 4) * 8]);
#pragma unroll
    for (int n = 0; n < 4; ++n)
#pragma unroll
      for (int ks = 0; ks < 4; ++ks) {
        bf16x8 vb = *(const bf16x8*)(&Vs[(n * 16 + (l & 15)) * LV + ks * 32 + (l >> 4) * 8]);
        oacc[n] = __builtin_amdgcn_mfma_f32_16x16x32_bf16(pa[ks], vb, oacc[n], 0, 0, 0);
      }
  }
  // epilogue: normalize, write og[h][s][d] (contiguous == reference reshape)
#pragma unroll
  for (int r = 0; r < 4; ++r) {
    float inv = 1.f / li[r];
    int srow = q0 + w * 16 + (l >> 4) * 4 + r;
#pragma unroll
    for (int n = 0; n < 4; ++n) {
      int d = n * 16 + (l & 15);
      og[(size_t)h * kS * kDK + (size_t)srow * kDK + d] = f2b(oacc[n][r] * inv);
    }
  }
}

extern "C" void kernel_launch(void* const* d_in, const int* in_sizes, int n_in,
                              void* d_out, int out_size, void* d_ws, size_t ws_size,
                              hipStream_t stream) {
  const float* x = (const float*)d_in[0];
  const float* wq = (const float*)d_in[1];
  const float* bq = (const float*)d_in[2];
  const float* wk = (const float*)d_in[3];
  const float* bk = (const float*)d_in[4];
  const float* wv = (const float*)d_in[5];
  const float* bv = (const float*)d_in[6];
  const float* wo = (const float*)d_in[7];
  const float* bo = (const float*)d_in[8];
  const float* w1 = (const float*)d_in[9];
  const float* b1 = (const float*)d_in[10];
  const float* w2 = (const float*)d_in[11];
  const float* b2 = (const float*)d_in[12];
  const float* ln1g = (const float*)d_in[13];
  const float* ln1b = (const float*)d_in[14];
  const float* ln2g = (const float*)d_in[15];
  const float* ln2b = (const float*)d_in[16];
  float* out = (float*)d_out;

  // Workspace plan. "pool" buffers are all dead by the time the split-K
  // partials are written, so partials alias pool base.
  char* p = (char*)d_ws;
  auto alloc = [&](size_t bytes) { void* q = (void*)p; p += (bytes + 255) & ~(size_t)255; return q; };
  u16* h1 = (u16*)alloc((size_t)kS * kD * 2);
  u16* wqkvt = (u16*)alloc((size_t)3 * kD * kD * 2);
  u16* qkv = (u16*)alloc((size_t)kS * 3 * kD * 2);
  u16* vt = (u16*)alloc((size_t)kH * kDK * kS * 2);
  u16* og = (u16*)alloc((size_t)kS * kD * 2);
  u16* wot = (u16*)alloc((size_t)kD * kD * 2);
  u16* h2 = (u16*)alloc((size_t)kS * kD * 2);
  u16* w1t = (u16*)alloc((size_t)kD * kMLP * 2);
  float* bqkv = (float*)alloc((size_t)3 * kD * 4);
  float* x2 = (float*)alloc((size_t)kS * kD * 4);
  u16* fbuf = (u16*)alloc((size_t)kS * kMLP * 2);
  u16* w2t = (u16*)alloc((size_t)kMLP * kD * 2);
  float* part = (float*)d_ws;  // aliases pool (see plan above)
  const size_t strideMN = (size_t)kS * kD;

  dim3 tb(32, 8);
  transpose_cvt<<<dim3(kD / 32, kD / 32), tb, 0, stream>>>(wq, wqkvt, kD, kD);
  transpose_cvt<<<dim3(kD / 32, kD / 32), tb, 0, stream>>>(wk, wqkvt + kD * kD, kD, kD);
  transpose_cvt<<<dim3(kD / 32, kD / 32), tb, 0, stream>>>(wv, wqkvt + 2 * kD * kD, kD, kD);
  transpose_cvt<<<dim3(kD / 32, kD / 32), tb, 0, stream>>>(wo, wot, kD, kD);
  transpose_cvt<<<dim3(kMLP / 32, kD / 32), tb, 0, stream>>>(w1, w1t, kD, kMLP);
  transpose_cvt<<<dim3(kD / 32, kMLP / 32), tb, 0, stream>>>(w2, w2t, kMLP, kD);
  concat_bias<<<dim3(12), dim3(256), 0, stream>>>(bq, bk, bv, bqkv);

  ln_kernel<<<dim3(kS), dim3(256), 0, stream>>>(x, ln1g, ln1b, h1);
  // fused QKV: [2048,1024] x [3072,1024]^T -> qkv bf16 [2048,3072]
  gemm_bt<0><<<dim3(3 * kD / 64, kS / 128, 1), dim3(256), 0, stream>>>(
      h1, wqkvt, bqkv, qkv, 3 * kD, kD, kD);
  vtrans<<<dim3(kS / 64, kH), dim3(256), 0, stream>>>(qkv, vt);
  flash_attn<<<dim3(kS / 64, kH), dim3(256), 0, stream>>>(qkv, vt, og);
  // O-proj split-K=2: partials = og @ wo  (fp32)
  gemm_bt<3><<<dim3(kD / 64, kS / 128, 2), dim3(256), 0, stream>>>(
      og, wot, nullptr, part, kD, kD, kD / 2);
  // x2 = x + part0 + part1 + bo
  reduce_add<2><<<dim3(kS * kD / 4 / 256), dim3(256), 0, stream>>>(
      part, bo, x, x2, kD, strideMN);
  ln_kernel<<<dim3(kS), dim3(256), 0, stream>>>(x2, ln2g, ln2b, h2);
  // FFN1 + exact GELU -> bf16 [2048,4096]
  gemm_bt<1><<<dim3(kMLP / 64, kS / 128, 1), dim3(256), 0, stream>>>(
      h2, w1t, b1, fbuf, kMLP, kD, kD);
  // FFN2 split-K=4: partials = gelu @ w2  (fp32)
  gemm_bt<3><<<dim3(kD / 64, kS / 128, 4), dim3(256), 0, stream>>>(
      fbuf, w2t, nullptr, part, kD, kMLP, kMLP / 4);
  // out = x2 + sum(parts) + b2
  reduce_add<4><<<dim3(kS * kD / 4 / 256), dim3(256), 0, stream>>>(
      part, b2, x2, out, kD, strideMN);
}

// Round 5
// 320.061 us; speedup vs baseline: 1.0432x; 1.0076x over previous
//
#include <hip/hip_runtime.h>

// EncoderBlock: pre-LN MHSA + pre-LN GELU FFN.  S=2048 D=1024 H=16 DK=64 MLP=4096.
// GEMMs: deep-pipelined bt-GEMM (A[M,K] x Bt[N,K]), 128x256 tile, 8 waves (512thr),
// BK=64, TRIPLE-buffered LDS (144KB), prefetch depth 2, ONE s_waitcnt vmcnt(6) and
// ONE s_barrier per K-step (T3/T4: counted vmcnt, never drained in-loop), setprio
// around MFMA clusters (T5), 3-bit XOR chunk swizzle (conflict-free ds_read_b128).
// N=1024 GEMMs (O-proj, FFN2) use split-K + fused reduce.
// Attention: round-0 proven flash kernel (64.5 us measured).

constexpr int kS = 2048, kD = 1024, kH = 16, kDK = 64, kMLP = 4096;
constexpr float kEps = 1e-5f;

using u16 = unsigned short;
using u32 = unsigned int;
typedef float f32x4 __attribute__((ext_vector_type(4)));
typedef short bf16x8 __attribute__((ext_vector_type(8)));   // 8 bf16 = 4 VGPRs

__device__ __forceinline__ u16 f2b(float f) {               // fp32 -> bf16 (RNE)
  u32 u = __builtin_bit_cast(u32, f);
  return (u16)((u + 0x7fffu + ((u >> 16) & 1u)) >> 16);
}

typedef const __attribute__((address_space(1))) u32* gas1;
typedef __attribute__((address_space(3))) u32* las3;
__device__ __forceinline__ void async16(const void* g, void* l) {
  // global -> LDS DMA, 16B/lane; LDS dest = wave-uniform base + lane*16
  __builtin_amdgcn_global_load_lds((gas1)g, (las3)l, 16, 0, 0);
}

// ---------------- LayerNorm: fp32 [row][1024] -> bf16 ----------------
__global__ __launch_bounds__(256)
void ln_kernel(const float* __restrict__ x, const float* __restrict__ g,
               const float* __restrict__ b, u16* __restrict__ out) {
  __shared__ float red[8];
  const int row = blockIdx.x, tid = threadIdx.x;
  const float4 v = *(const float4*)(x + (size_t)row * kD + tid * 4);
  float s = v.x + v.y + v.z + v.w;
  float ss = v.x * v.x + v.y * v.y + v.z * v.z + v.w * v.w;
#pragma unroll
  for (int d = 1; d < 64; d <<= 1) { s += __shfl_xor(s, d); ss += __shfl_xor(ss, d); }
  if ((tid & 63) == 0) { red[tid >> 6] = s; red[4 + (tid >> 6)] = ss; }
  __syncthreads();
  const float m = (red[0] + red[1] + red[2] + red[3]) * (1.f / kD);
  const float var = (red[4] + red[5] + red[6] + red[7]) * (1.f / kD) - m * m;
  const float r = rsqrtf(var + kEps);
  const float4 gv = *(const float4*)(g + tid * 4);
  const float4 bv = *(const float4*)(b + tid * 4);
  ushort4 o;
  o.x = f2b((v.x - m) * r * gv.x + bv.x);
  o.y = f2b((v.y - m) * r * gv.y + bv.y);
  o.z = f2b((v.z - m) * r * gv.z + bv.z);
  o.w = f2b((v.w - m) * r * gv.w + bv.w);
  *(ushort4*)(out + (size_t)row * kD + tid * 4) = o;
}

// ------------- transpose + fp32->bf16:  out[c][r] = in[r][c] -------------
__global__ __launch_bounds__(256)
void transpose_cvt(const float* __restrict__ in, u16* __restrict__ out, int R, int C) {
  __shared__ float tile[32][33];
  const int c0 = blockIdx.x * 32, r0 = blockIdx.y * 32;
  const int x = threadIdx.x, y = threadIdx.y;
#pragma unroll
  for (int i = 0; i < 4; ++i)
    tile[y + i * 8][x] = in[(size_t)(r0 + y + i * 8) * C + c0 + x];
  __syncthreads();
#pragma unroll
  for (int i = 0; i < 4; ++i)
    out[(size_t)(c0 + y + i * 8) * R + r0 + x] = f2b(tile[x][y + i * 8]);
}

__global__ void concat_bias(const float* __restrict__ bq, const float* __restrict__ bk,
                            const float* __restrict__ bv, float* __restrict__ out) {
  int i = blockIdx.x * 256 + threadIdx.x;  // 3072
  out[i] = i < kD ? bq[i] : (i < 2 * kD ? bk[i - kD] : bv[i - 2 * kD]);
}

// --- per-head V transpose: qkv[s][2048+h*64+d] (bf16) -> vt[h][d][s] (bf16) ---
__global__ __launch_bounds__(256)
void vtrans(const u16* __restrict__ qkv, u16* __restrict__ vt) {
  __shared__ u16 t[64][72];
  const int s0 = blockIdx.x * 64, h = blockIdx.y, tid = threadIdx.x;
#pragma unroll
  for (int r = 0; r < 2; ++r) {
    int chunk = r * 256 + tid, row = chunk >> 3, col = (chunk & 7) * 8;
    uint4 v = *(const uint4*)(qkv + (size_t)(s0 + row) * 3072 + 2 * kD + h * 64 + col);
    *(uint4*)(&t[row][col]) = v;
  }
  __syncthreads();
#pragma unroll
  for (int r = 0; r < 2; ++r) {
    int chunk = r * 256 + tid, drow = chunk >> 3, scol = (chunk & 7) * 8;
    u16 tmp[8];
#pragma unroll
    for (int j = 0; j < 8; ++j) tmp[j] = t[scol + j][drow];
    *(uint4*)(vt + (size_t)h * 64 * kS + (size_t)drow * kS + s0 + scol) = *(uint4*)tmp;
  }
}

// ---------------- bt-GEMM: C[M,N] = A[M,K](bf16) x Bt[N,K](bf16) ----------------
// 128x256 tile, BK=64, 8 waves (2M x 4N, each 64x64 out), 32 MFMA/K-step/wave.
// LDS layout per tile: [row][chunk ^ (row&7)] with 8 chunks of 8 bf16 (16B).
// Triple buffer, prefetch depth 2: iter t reads buf[t%3], stages t+2 into
// buf[(t+2)%3]; per iter exactly one s_waitcnt vmcnt(6) (leaves t+2's 6 DMAs
// in flight; drains t+1's) and one s_barrier.
// ds_read_b128 conflict-free: per 16-lane group, chunk=(ks*4+q)^(ln&7) spreads
// 8 distinct 16B cols x 2 rows (8 apart, same banks) = 2 lanes/bank = free.
// EPI 0: bf16 out (+bias)   EPI 1: bf16 gelu_erf out (+bias)
// EPI 3: fp32 partial store (split-K via blockIdx.z; no bias)
template <int EPI>
__global__ __launch_bounds__(512, 1)
void gemm_bt(const u16* __restrict__ A, const u16* __restrict__ Bt,
             const float* __restrict__ bias, void* __restrict__ Cout,
             int N, int K, int Ksub) {
  constexpr int BM = 128, BN = 256, BK = 64;
  __shared__ u16 As[3][BM * BK];   // 3 x 16 KB
  __shared__ u16 Bs[3][BN * BK];   // 3 x 32 KB   (total 144 KB)
  const int tid = threadIdx.x;
  const int w = tid >> 6, l = tid & 63;
  const int wm = w >> 2, wn = w & 3;           // 2 x 4 wave grid
  const int ln = l & 15, q = l >> 4;
  const int row0 = blockIdx.y * BM, col0 = blockIdx.x * BN;
  const int koff = blockIdx.z * Ksub;
  const int nIter = Ksub / BK;

  // staging: call c covers rows c*64 + (tid>>3); LDS dest linear (tid*16B within
  // call region); source chunk pre-inverse-swizzled: (tid&7) ^ (row&7).
  const int rS = tid >> 3;
  const int cS = ((tid & 7) ^ (rS & 7)) * 8;
  const u16* Ab0 = A + (size_t)(row0 + rS) * K + koff + cS;
  const u16* Bb0 = Bt + (size_t)(col0 + rS) * K + koff + cS;
  const int dW = w * 512;                      // wave's u16 offset in a call region

  f32x4 acc[4][4] = {};

  auto stage = [&](int t, int b) {             // 6 async16 per wave
    const int kt = t * BK;
    async16(Ab0 + kt, &As[b][dW]);
    async16(Ab0 + (size_t)64 * K + kt, &As[b][4096 + dW]);
    async16(Bb0 + kt, &Bs[b][dW]);
    async16(Bb0 + (size_t)64 * K + kt, &Bs[b][4096 + dW]);
    async16(Bb0 + (size_t)128 * K + kt, &Bs[b][8192 + dW]);
    async16(Bb0 + (size_t)192 * K + kt, &Bs[b][12288 + dW]);
  };

  stage(0, 0);
  stage(1, 1);
  asm volatile("s_waitcnt vmcnt(6)" ::: "memory");   // tile 0 landed; tile 1 in flight
  __builtin_amdgcn_s_barrier();
  __builtin_amdgcn_sched_barrier(0);

  int bR = 0, bW = 2;
  for (int t = 0; t < nIter; ++t) {
    if (t + 2 < nIter) stage(t + 2, bW);
    const u16* Ar = As[bR];
    const u16* Br = Bs[bR];
#pragma unroll
    for (int ks = 0; ks < 2; ++ks) {
      const int ch = ((ks * 4 + q) ^ (ln & 7)) * 8;
      bf16x8 af[4], bf[4];
#pragma unroll
      for (int i = 0; i < 4; ++i)
        af[i] = *(const bf16x8*)(Ar + (wm * 64 + i * 16 + ln) * 64 + ch);
#pragma unroll
      for (int j = 0; j < 4; ++j)
        bf[j] = *(const bf16x8*)(Br + (wn * 64 + j * 16 + ln) * 64 + ch);
      __builtin_amdgcn_s_setprio(1);
#pragma unroll
      for (int i = 0; i < 4; ++i)
#pragma unroll
        for (int j = 0; j < 4; ++j)
          acc[i][j] = __builtin_amdgcn_mfma_f32_16x16x32_bf16(af[i], bf[j], acc[i][j], 0, 0, 0);
      __builtin_amdgcn_s_setprio(0);
    }
    // counted drain: t+1's 6 DMAs done, t+2's 6 stay in flight (never 0 mid-loop)
    if (t + 2 < nIter) asm volatile("s_waitcnt vmcnt(6)" ::: "memory");
    else               asm volatile("s_waitcnt vmcnt(0)" ::: "memory");
    __builtin_amdgcn_s_barrier();
    __builtin_amdgcn_sched_barrier(0);
    bR = bR == 2 ? 0 : bR + 1;
    bW = bW == 2 ? 0 : bW + 1;
  }

  float* Pf = nullptr;
  if constexpr (EPI == 3)
    Pf = (float*)Cout + (size_t)blockIdx.z * gridDim.y * BM * N;
#pragma unroll
  for (int i = 0; i < 4; ++i) {
    const int row = row0 + wm * 64 + i * 16 + q * 4;
#pragma unroll
    for (int j = 0; j < 4; ++j) {
      const int col = col0 + wn * 64 + j * 16 + ln;
      float bb = 0.f;
      if constexpr (EPI != 3) bb = bias[col];
#pragma unroll
      for (int r = 0; r < 4; ++r) {
        const size_t idx = (size_t)(row + r) * N + col;
        float v = acc[i][j][r] + bb;
        if constexpr (EPI == 0) {
          ((u16*)Cout)[idx] = f2b(v);
        } else if constexpr (EPI == 1) {
          ((u16*)Cout)[idx] = f2b(0.5f * v * (1.f + erff(v * 0.7071067811865475f)));
        } else {
          Pf[idx] = v;
        }
      }
    }
  }
}

// ---- split-K reduce: out = sum_s parts[s] + bias + res  (fp32, float4) ----
template <int KS>
__global__ __launch_bounds__(256)
void reduce_add(const float* __restrict__ parts, const float* __restrict__ bias,
                const float* __restrict__ res, float* __restrict__ out,
                int N, size_t strideMN) {
  const size_t b = ((size_t)blockIdx.x * 256 + threadIdx.x) * 4;
  float4 a = *(const float4*)(res + b);
  const float4 bv = *(const float4*)(bias + (b & (size_t)(N - 1)));
  a.x += bv.x; a.y += bv.y; a.z += bv.z; a.w += bv.w;
#pragma unroll
  for (int s = 0; s < KS; ++s) {
    const float4 p = *(const float4*)(parts + s * strideMN + b);
    a.x += p.x; a.y += p.y; a.z += p.z; a.w += p.w;
  }
  *(float4*)(out + b) = a;
}

// ---------------- flash attention (round-0 proven version) ----------------
// grid (S/64, H), 256 thr (4 waves); wave w owns q-rows [q0+w*16, +16).
__global__ __launch_bounds__(256, 2)
void flash_attn(const u16* __restrict__ qkv, const u16* __restrict__ vt,
                u16* __restrict__ og) {
  constexpr int LQ = 72;    // 64 + 8 pad (breaks b128 bank conflicts)
  constexpr int LV = 136;   // 128 + 8 pad
  __shared__ u16 Qs[64 * LQ];
  __shared__ u16 Ks[128 * LQ];
  __shared__ u16 Vs[64 * LV];       // V^T tile: [d][s]
  __shared__ u16 Ps[4][16 * LV];    // per-wave P (C-layout -> A-layout round trip)
  const int tid = threadIdx.x, w = tid >> 6, l = tid & 63;
  const int h = blockIdx.y, q0 = blockIdx.x * 64;

  // stage Q [64][64]
#pragma unroll
  for (int r = 0; r < 2; ++r) {
    int chunk = r * 256 + tid, row = chunk >> 3, col = (chunk & 7) * 8;
    uint4 v = *(const uint4*)(qkv + (size_t)(q0 + row) * 3072 + h * 64 + col);
    *(uint4*)(&Qs[row * LQ + col]) = v;
  }
  __syncthreads();
  bf16x8 qa[2];
#pragma unroll
  for (int kq = 0; kq < 2; ++kq)
    qa[kq] = *(const bf16x8*)(&Qs[(w * 16 + (l & 15)) * LQ + kq * 32 + (l >> 4) * 8]);

  f32x4 oacc[4] = {};
  float mi[4], li[4];
#pragma unroll
  for (int r = 0; r < 4; ++r) { mi[r] = -1e30f; li[r] = 0.f; }

  for (int kt = 0; kt < kS; kt += 128) {
    __syncthreads();  // prev iter done reading Ks/Vs
    // stage K-tile [128][64]
#pragma unroll
    for (int r = 0; r < 4; ++r) {
      int chunk = r * 256 + tid, row = chunk >> 3, col = (chunk & 7) * 8;
      uint4 v = *(const uint4*)(qkv + (size_t)(kt + row) * 3072 + kD + h * 64 + col);
      *(uint4*)(&Ks[row * LQ + col]) = v;
    }
    // stage V^T tile [64][128]
#pragma unroll
    for (int r = 0; r < 4; ++r) {
      int chunk = r * 256 + tid, row = chunk >> 4, col = (chunk & 15) * 8;
      uint4 v = *(const uint4*)(vt + (size_t)h * 64 * kS + (size_t)row * kS + kt + col);
      *(uint4*)(&Vs[row * LV + col]) = v;
    }
    __syncthreads();

    // S = Q K^T  (16 q-rows x 128 cols per wave)
    f32x4 s[8];
#pragma unroll
    for (int n = 0; n < 8; ++n) {
      f32x4 z = {};
      bf16x8 kb0 = *(const bf16x8*)(&Ks[(n * 16 + (l & 15)) * LQ + (l >> 4) * 8]);
      bf16x8 kb1 = *(const bf16x8*)(&Ks[(n * 16 + (l & 15)) * LQ + 32 + (l >> 4) * 8]);
      z = __builtin_amdgcn_mfma_f32_16x16x32_bf16(qa[0], kb0, z, 0, 0, 0);
      z = __builtin_amdgcn_mfma_f32_16x16x32_bf16(qa[1], kb1, z, 0, 0, 0);
      s[n] = z;
    }
    // online softmax (rows live on 16 lanes sharing l>>4; cols = l&15 across 8 frags)
    float alpha[4];
#pragma unroll
    for (int r = 0; r < 4; ++r) {
      float m = -1e30f;
#pragma unroll
      for (int n = 0; n < 8; ++n) m = fmaxf(m, s[n][r]);
#pragma unroll
      for (int d = 1; d < 16; d <<= 1) m = fmaxf(m, __shfl_xor(m, d));
      m *= 0.125f;  // 1/sqrt(DK); positive scale commutes with max
      float mn = fmaxf(mi[r], m);
      alpha[r] = __expf(mi[r] - mn);
      mi[r] = mn;
      li[r] *= alpha[r];
    }
#pragma unroll
    for (int n = 0; n < 4; ++n)
#pragma unroll
      for (int r = 0; r < 4; ++r) oacc[n][r] *= alpha[r];
    float rs[4] = {0.f, 0.f, 0.f, 0.f};
#pragma unroll
    for (int n = 0; n < 8; ++n)
#pragma unroll
      for (int r = 0; r < 4; ++r) {
        float pv = __expf(s[n][r] * 0.125f - mi[r]);
        rs[r] += pv;
        Ps[w][((l >> 4) * 4 + r) * LV + n * 16 + (l & 15)] = f2b(pv);
      }
#pragma unroll
    for (int r = 0; r < 4; ++r) {
      float t = rs[r];
#pragma unroll
      for (int d = 1; d < 16; d <<= 1) t += __shfl_xor(t, d);
      li[r] += t;
    }
    // O += P V   (P 16x128 from own-wave LDS region; V^T in Vs)
    bf16x8 pa[4];
#pragma unroll
    for (int ks = 0; ks < 4; ++ks)
      pa[ks] = *(const bf16x8*)(&Ps[w][(l & 15) * LV + ks * 32 + (l >> 4) * 8]);
#pragma unroll
    for (int n = 0; n < 4; ++n)
#pragma unroll
      for (int ks = 0; ks < 4; ++ks) {
        bf16x8 vb = *(const bf16x8*)(&Vs[(n * 16 + (l & 15)) * LV + ks * 32 + (l >> 4) * 8]);
        oacc[n] = __builtin_amdgcn_mfma_f32_16x16x32_bf16(pa[ks], vb, oacc[n], 0, 0, 0);
      }
  }
  // epilogue: normalize, write og[h][s][d] (contiguous == reference reshape)
#pragma unroll
  for (int r = 0; r < 4; ++r) {
    float inv = 1.f / li[r];
    int srow = q0 + w * 16 + (l >> 4) * 4 + r;
#pragma unroll
    for (int n = 0; n < 4; ++n) {
      int d = n * 16 + (l & 15);
      og[(size_t)h * kS * kDK + (size_t)srow * kDK + d] = f2b(oacc[n][r] * inv);
    }
  }
}

extern "C" void kernel_launch(void* const* d_in, const int* in_sizes, int n_in,
                              void* d_out, int out_size, void* d_ws, size_t ws_size,
                              hipStream_t stream) {
  const float* x = (const float*)d_in[0];
  const float* wq = (const float*)d_in[1];
  const float* bq = (const float*)d_in[2];
  const float* wk = (const float*)d_in[3];
  const float* bk = (const float*)d_in[4];
  const float* wv = (const float*)d_in[5];
  const float* bv = (const float*)d_in[6];
  const float* wo = (const float*)d_in[7];
  const float* bo = (const float*)d_in[8];
  const float* w1 = (const float*)d_in[9];
  const float* b1 = (const float*)d_in[10];
  const float* w2 = (const float*)d_in[11];
  const float* b2 = (const float*)d_in[12];
  const float* ln1g = (const float*)d_in[13];
  const float* ln1b = (const float*)d_in[14];
  const float* ln2g = (const float*)d_in[15];
  const float* ln2b = (const float*)d_in[16];
  float* out = (float*)d_out;

  // Workspace plan. "pool" buffers are all dead by the time the split-K
  // partials are written, so partials alias pool base.
  char* p = (char*)d_ws;
  auto alloc = [&](size_t bytes) { void* q = (void*)p; p += (bytes + 255) & ~(size_t)255; return q; };
  u16* h1 = (u16*)alloc((size_t)kS * kD * 2);
  u16* wqkvt = (u16*)alloc((size_t)3 * kD * kD * 2);
  u16* qkv = (u16*)alloc((size_t)kS * 3 * kD * 2);
  u16* vt = (u16*)alloc((size_t)kH * kDK * kS * 2);
  u16* og = (u16*)alloc((size_t)kS * kD * 2);
  u16* wot = (u16*)alloc((size_t)kD * kD * 2);
  u16* h2 = (u16*)alloc((size_t)kS * kD * 2);
  u16* w1t = (u16*)alloc((size_t)kD * kMLP * 2);
  float* bqkv = (float*)alloc((size_t)3 * kD * 4);
  float* x2 = (float*)alloc((size_t)kS * kD * 4);
  u16* fbuf = (u16*)alloc((size_t)kS * kMLP * 2);
  u16* w2t = (u16*)alloc((size_t)kMLP * kD * 2);
  float* part = (float*)d_ws;  // aliases pool (see plan above)
  const size_t strideMN = (size_t)kS * kD;

  dim3 tb(32, 8);
  transpose_cvt<<<dim3(kD / 32, kD / 32), tb, 0, stream>>>(wq, wqkvt, kD, kD);
  transpose_cvt<<<dim3(kD / 32, kD / 32), tb, 0, stream>>>(wk, wqkvt + kD * kD, kD, kD);
  transpose_cvt<<<dim3(kD / 32, kD / 32), tb, 0, stream>>>(wv, wqkvt + 2 * kD * kD, kD, kD);
  transpose_cvt<<<dim3(kD / 32, kD / 32), tb, 0, stream>>>(wo, wot, kD, kD);
  transpose_cvt<<<dim3(kMLP / 32, kD / 32), tb, 0, stream>>>(w1, w1t, kD, kMLP);
  transpose_cvt<<<dim3(kD / 32, kMLP / 32), tb, 0, stream>>>(w2, w2t, kMLP, kD);
  concat_bias<<<dim3(12), dim3(256), 0, stream>>>(bq, bk, bv, bqkv);

  ln_kernel<<<dim3(kS), dim3(256), 0, stream>>>(x, ln1g, ln1b, h1);
  // fused QKV: [2048,1024] x [3072,1024]^T -> qkv bf16 [2048,3072]
  gemm_bt<0><<<dim3(3 * kD / 256, kS / 128, 1), dim3(512), 0, stream>>>(
      h1, wqkvt, bqkv, qkv, 3 * kD, kD, kD);
  vtrans<<<dim3(kS / 64, kH), dim3(256), 0, stream>>>(qkv, vt);
  flash_attn<<<dim3(kS / 64, kH), dim3(256), 0, stream>>>(qkv, vt, og);
  // O-proj split-K=2: partials = og @ wo  (fp32)
  gemm_bt<3><<<dim3(kD / 256, kS / 128, 2), dim3(512), 0, stream>>>(
      og, wot, nullptr, part, kD, kD, kD / 2);
  // x2 = x + part0 + part1 + bo
  reduce_add<2><<<dim3(kS * kD / 4 / 256), dim3(256), 0, stream>>>(
      part, bo, x, x2, kD, strideMN);
  ln_kernel<<<dim3(kS), dim3(256), 0, stream>>>(x2, ln2g, ln2b, h2);
  // FFN1 + exact GELU -> bf16 [2048,4096]
  gemm_bt<1><<<dim3(kMLP / 256, kS / 128, 1), dim3(512), 0, stream>>>(
      h2, w1t, b1, fbuf, kMLP, kD, kD);
  // FFN2 split-K=4: partials = gelu @ w2  (fp32)
  gemm_bt<3><<<dim3(kD / 256, kS / 128, 4), dim3(512), 0, stream>>>(
      fbuf, w2t, nullptr, part, kD, kMLP, kMLP / 4);
  // out = x2 + sum(parts) + b2
  reduce_add<4><<<dim3(kS * kD / 4 / 256), dim3(256), 0, stream>>>(
      part, b2, x2, out, kD, strideMN);
}